// Round 1
// baseline (3687.627 us; speedup 1.0000x reference)
//
#include <hip/hip_runtime.h>
#include <hip/hip_bf16.h>

#define N_NODES 32768
#define F_DIM 64
#define H_HEADS 4
#define HF 256
#define ES_EDGES 524288
#define EG_EDGES 524288
#define E2_EDGES (EG_EDGES + N_NODES)
#define G_GRAPHS 64
#define NC_OUT 10
#define BN_EPS 1e-5f
#define NH (N_NODES * H_HEADS)
#define E2H (E2_EDGES * H_HEADS)

__device__ __forceinline__ float eluf(float x) { return x > 0.f ? x : expm1f(x); }
__device__ __forceinline__ float lreluf(float x) { return x > 0.f ? x : 0.2f * x; }
__device__ __forceinline__ unsigned encf(float f) {
    unsigned u = __float_as_uint(f);
    return (u & 0x80000000u) ? ~u : (u | 0x80000000u);
}
__device__ __forceinline__ float decf(unsigned u) {
    return __uint_as_float((u & 0x80000000u) ? (u ^ 0x80000000u) : ~u);
}

// out[dst[e]][f] += attr[e] * (abs?) x[src[e]][f]   (one wave per edge, lane=f)
__global__ void k_scatter(const float* __restrict__ x, const int* __restrict__ src,
                          const int* __restrict__ dst, const float* __restrict__ attr,
                          float* __restrict__ out, int E, int do_abs) {
    int t = blockIdx.x * 256 + threadIdx.x;
    int e = t >> 6, f = t & 63;
    if (e >= E) return;
    int s = src[e], d = dst[e];
    float v = x[s * 64 + f];
    if (do_abs) v = fabsf(v);
    unsafeAtomicAdd(&out[d * 64 + f], attr[e] * v);
}

// a_s[n,h] = sum_f h[n,h,f]*asrc[h,f]; same for a_d. One wave per (n,h).
__global__ void k_attn_coef(const float* __restrict__ h, const float* __restrict__ asrc,
                            const float* __restrict__ adst, float* __restrict__ a_s,
                            float* __restrict__ a_d) {
    int t = blockIdx.x * 256 + threadIdx.x;
    int w = t >> 6, lane = t & 63;
    int hd = w & 3;
    float hv = h[(size_t)w * 64 + lane];
    float s1 = hv * asrc[hd * 64 + lane];
    float s2 = hv * adst[hd * 64 + lane];
    for (int off = 32; off; off >>= 1) {
        s1 += __shfl_xor(s1, off);
        s2 += __shfl_xor(s2, off);
    }
    if (lane == 0) { a_s[w] = s1; a_d[w] = s2; }
}

__global__ void k_fill_u32(unsigned* __restrict__ p, unsigned v, int n) {
    int t = blockIdx.x * 256 + threadIdx.x;
    if (t < n) p[t] = v;
}

// segment max of leaky_relu(a_s[src]+a_d[dst]) over dst, per head
__global__ void k_attn_max(const int* __restrict__ ei, const float* __restrict__ a_s,
                           const float* __restrict__ a_d, unsigned* __restrict__ menc) {
    int t = blockIdx.x * 256 + threadIdx.x;
    int e = t >> 2, hd = t & 3;
    if (e >= E2_EDGES) return;
    int s, d;
    if (e < EG_EDGES) { s = ei[e]; d = ei[EG_EDGES + e]; }
    else { s = d = e - EG_EDGES; }
    float ev = lreluf(a_s[s * 4 + hd] + a_d[d * 4 + hd]);
    atomicMax(&menc[d * 4 + hd], encf(ev));
}

// ex = exp(e - m[dst]); store ex, accumulate denom
__global__ void k_attn_exp(const int* __restrict__ ei, const float* __restrict__ a_s,
                           const float* __restrict__ a_d, const unsigned* __restrict__ menc,
                           float* __restrict__ exbuf, float* __restrict__ denom) {
    int t = blockIdx.x * 256 + threadIdx.x;
    int e = t >> 2, hd = t & 3;
    if (e >= E2_EDGES) return;
    int s, d;
    if (e < EG_EDGES) { s = ei[e]; d = ei[EG_EDGES + e]; }
    else { s = d = e - EG_EDGES; }
    float ev = lreluf(a_s[s * 4 + hd] + a_d[d * 4 + hd]);
    float m = decf(menc[d * 4 + hd]);
    float ex = expf(ev - m);
    exbuf[t] = ex;
    unsafeAtomicAdd(&denom[d * 4 + hd], ex);
}

// gat_out[dst,h,:] += (ex/denom[dst,h]) * hmat[src,h,:]  (one wave per (edge,head))
__global__ void k_attn_agg(const int* __restrict__ ei, const float* __restrict__ hmat,
                           const float* __restrict__ exbuf, const float* __restrict__ denom,
                           float* __restrict__ gout) {
    int t = blockIdx.x * 256 + threadIdx.x;
    int w = t >> 6, f = t & 63;
    int e = w >> 2, hd = w & 3;
    if (e >= E2_EDGES) return;
    int s, d;
    if (e < EG_EDGES) { s = ei[e]; d = ei[EG_EDGES + e]; }
    else { s = d = e - EG_EDGES; }
    float alpha = exbuf[w] / denom[d * 4 + hd];
    float hv = hmat[(size_t)s * 256 + hd * 64 + f];
    unsafeAtomicAdd(&gout[(size_t)d * 256 + hd * 64 + f], alpha * hv);
}

// C[M,Nc] = op(A)[M,K] @ B[K,Nc] (+cbias). TRANSFORM=1: op(A)=elu(A+abias[k]).
// BM=BN=64, BK=16, 256 threads, 4x4 per thread. M%64==0, Nc%64==0, K%16==0.
template <int TRANSFORM>
__global__ void k_gemm(const float* __restrict__ A, const float* __restrict__ B,
                       float* __restrict__ C, const float* __restrict__ abias,
                       const float* __restrict__ cbias, int M, int K, int Nc) {
    __shared__ float As[16][68];
    __shared__ float Bs[16][64];
    int bm = blockIdx.x * 64;
    int bn = blockIdx.y * 64;
    int tid = threadIdx.x;
    int tx = tid & 15, ty = tid >> 4;
    float acc[4][4] = {};
    for (int k0 = 0; k0 < K; k0 += 16) {
        {
            int m = tid >> 2, k4 = (tid & 3) * 4;
            float4 v = *(const float4*)&A[(size_t)(bm + m) * K + k0 + k4];
            if (TRANSFORM == 1) {
                v.x = eluf(v.x + abias[k0 + k4 + 0]);
                v.y = eluf(v.y + abias[k0 + k4 + 1]);
                v.z = eluf(v.z + abias[k0 + k4 + 2]);
                v.w = eluf(v.w + abias[k0 + k4 + 3]);
            }
            As[k4 + 0][m] = v.x; As[k4 + 1][m] = v.y;
            As[k4 + 2][m] = v.z; As[k4 + 3][m] = v.w;
        }
        {
            int k = tid >> 4, n4 = (tid & 15) * 4;
            *(float4*)&Bs[k][n4] = *(const float4*)&B[(size_t)(k0 + k) * Nc + bn + n4];
        }
        __syncthreads();
#pragma unroll
        for (int k = 0; k < 16; ++k) {
            float4 a = *(const float4*)&As[k][ty * 4];
            float4 b = *(const float4*)&Bs[k][tx * 4];
            acc[0][0] += a.x * b.x; acc[0][1] += a.x * b.y; acc[0][2] += a.x * b.z; acc[0][3] += a.x * b.w;
            acc[1][0] += a.y * b.x; acc[1][1] += a.y * b.y; acc[1][2] += a.y * b.z; acc[1][3] += a.y * b.w;
            acc[2][0] += a.z * b.x; acc[2][1] += a.z * b.y; acc[2][2] += a.z * b.z; acc[2][3] += a.z * b.w;
            acc[3][0] += a.w * b.x; acc[3][1] += a.w * b.y; acc[3][2] += a.w * b.z; acc[3][3] += a.w * b.w;
        }
        __syncthreads();
    }
#pragma unroll
    for (int i = 0; i < 4; ++i)
#pragma unroll
        for (int j = 0; j < 4; ++j) {
            float cb = cbias ? cbias[bn + tx * 4 + j] : 0.f;
            C[(size_t)(bm + ty * 4 + i) * Nc + bn + tx * 4 + j] = acc[i][j] + cb;
        }
}

// column sums/sumsq of z [N,64]
__global__ void k_colstats(const float* __restrict__ z, float* __restrict__ sums,
                           float* __restrict__ sumsq) {
    int col = threadIdx.x & 63, rg = threadIdx.x >> 6;
    int base = blockIdx.x * 512;
    float s = 0.f, sq = 0.f;
    for (int r = base + rg; r < base + 512; r += 4) {
        float v = z[(size_t)r * 64 + col];
        s += v; sq += v * v;
    }
    __shared__ float ls[256], lq[256];
    ls[threadIdx.x] = s; lq[threadIdx.x] = sq;
    __syncthreads();
    if (threadIdx.x < 64) {
        int c = threadIdx.x;
        float ts = ls[c] + ls[c + 64] + ls[c + 128] + ls[c + 192];
        float tq = lq[c] + lq[c + 64] + lq[c + 128] + lq[c + 192];
        unsafeAtomicAdd(&sums[c], ts);
        unsafeAtomicAdd(&sumsq[c], tq);
    }
}

// x_acc += batchnorm(z)
__global__ void k_bn_acc(const float* __restrict__ z, const float* __restrict__ sums,
                         const float* __restrict__ sumsq, const float* __restrict__ g,
                         const float* __restrict__ beta, float* __restrict__ xacc) {
    int t = blockIdx.x * 256 + threadIdx.x;
    int col = t & 63;
    const float invN = 1.f / (float)N_NODES;
    float mu = sums[col] * invN;
    float var = sumsq[col] * invN - mu * mu;
    float sc = g[col] * rsqrtf(var + BN_EPS);
    xacc[t] += (z[t] - mu) * sc + beta[col];
}

// global_add_pool via run-length accumulate (batch is sorted)
__global__ void k_pool(const float* __restrict__ xa, const int* __restrict__ batch,
                       float* __restrict__ pooled) {
    int col = threadIdx.x & 63, rg = threadIdx.x >> 6;
    int r0 = blockIdx.x * 512 + rg * 128;
    int cur = -1;
    float acc = 0.f;
    for (int r = r0; r < r0 + 128; ++r) {
        int g = batch[r];
        if (g != cur) {
            if (cur >= 0) unsafeAtomicAdd(&pooled[cur * 64 + col], acc);
            cur = g; acc = 0.f;
        }
        acc += xa[(size_t)r * 64 + col];
    }
    if (cur >= 0) unsafeAtomicAdd(&pooled[cur * 64 + col], acc);
}

// naive small GEMM: C[M,Nc] = A[M,K]@B[K,Nc] + bias
__global__ void k_fc(const float* __restrict__ A, const float* __restrict__ B,
                     const float* __restrict__ bias, float* __restrict__ C,
                     int M, int K, int Nc) {
    int t = blockIdx.x * 256 + threadIdx.x;
    if (t >= M * Nc) return;
    int m = t / Nc, n = t % Nc;
    float s = bias[n];
    for (int k = 0; k < K; ++k) s += A[m * K + k] * B[k * Nc + n];
    C[t] = s;
}

// batchnorm over M rows (M=64) x C cols, optional relu; single block, 1 thread/col
__global__ void k_bn_small(const float* __restrict__ Y, const float* __restrict__ g,
                           const float* __restrict__ beta, int M, int C, int relu,
                           float* __restrict__ out) {
    int c = threadIdx.x;
    if (c >= C) return;
    float s = 0.f, sq = 0.f;
    for (int m = 0; m < M; ++m) {
        float v = Y[m * C + c];
        s += v; sq += v * v;
    }
    float mu = s / (float)M;
    float var = sq / (float)M - mu * mu;
    float sc = g[c] * rsqrtf(var + BN_EPS);
    for (int m = 0; m < M; ++m) {
        float v = (Y[m * C + c] - mu) * sc + beta[c];
        if (relu) v = fmaxf(v, 0.f);
        out[m * C + c] = v;
    }
}

extern "C" void kernel_launch(void* const* d_in, const int* in_sizes, int n_in,
                              void* d_out, int out_size, void* d_ws, size_t ws_size,
                              hipStream_t stream) {
    const float* x        = (const float*)d_in[0];
    const int*   ei       = (const int*)d_in[1];
    const int*   batch    = (const int*)d_in[2];
    const int*   sidx     = (const int*)d_in[3];
    const float* sattr    = (const float*)d_in[4];
    const float* gat_W    = (const float*)d_in[5];
    const float* gat_asrc = (const float*)d_in[6];
    const float* gat_adst = (const float*)d_in[7];
    const float* gat_b    = (const float*)d_in[8];
    const float* mlp_W    = (const float*)d_in[9];
    const float* mlp_b    = (const float*)d_in[10];
    const float* mlp_g    = (const float*)d_in[11];
    const float* mlp_beta = (const float*)d_in[12];
    const float* fc1_W    = (const float*)d_in[13];
    const float* fc1_b    = (const float*)d_in[14];
    const float* fc1_g    = (const float*)d_in[15];
    const float* fc1_beta = (const float*)d_in[16];
    const float* fc2_W    = (const float*)d_in[17];
    const float* fc2_b    = (const float*)d_in[18];
    const float* fc2_g    = (const float*)d_in[19];
    const float* fc2_beta = (const float*)d_in[20];
    const float* fc3_W    = (const float*)d_in[21];
    const float* fc3_b    = (const float*)d_in[22];
    const float* fc3_g    = (const float*)d_in[23];
    const float* fc3_beta = (const float*)d_in[24];

    float* ws = (float*)d_ws;
    const size_t NF = (size_t)N_NODES * F_DIM;
    float*    xs    = ws;                     // 4*NF
    float*    hbuf  = ws + 4 * NF;            // 4*NF (also xh1..3 staging)
    float*    gout  = ws + 8 * NF;            // 4*NF
    float*    zbuf  = ws + 12 * NF;           // NF
    float*    xacc  = ws + 13 * NF;           // NF
    float*    a_s   = ws + 14 * NF;           // NH
    float*    a_d   = a_s + NH;               // NH
    unsigned* menc  = (unsigned*)(a_d + NH);  // NH
    float*    denom = (float*)(menc) + NH;    // NH
    float*    exbuf = denom + NH;             // E2H
    float*    sums  = exbuf + E2H;            // 64
    float*    sumsq = sums + 64;              // 64
    float*    pooled= sumsq + 64;             // 4096
    float*    h1    = pooled + G_GRAPHS * F_DIM; // 16384
    float*    h2    = h1 + 64 * 256;          // 8192
    float*    f3    = h2 + 64 * 128;          // 640

    hipMemsetAsync(xs, 0, 4 * NF * sizeof(float), stream);
    hipMemsetAsync(hbuf, 0, 3 * NF * sizeof(float), stream);

    const int scb = ES_EDGES * 64 / 256;
    // x0 = scatter(idx0, attr0, x)
    k_scatter<<<scb, 256, 0, stream>>>(x, sidx, sidx + ES_EDGES, sattr, xs, ES_EDGES, 0);
    // xh_i (raw; abs applied on read in second pass)
    for (int i = 1; i < 4; ++i)
        k_scatter<<<scb, 256, 0, stream>>>(x, sidx + (size_t)i * 2 * ES_EDGES,
                                           sidx + (size_t)i * 2 * ES_EDGES + ES_EDGES,
                                           sattr + (size_t)i * ES_EDGES,
                                           hbuf + (size_t)(i - 1) * NF, ES_EDGES, 0);
    // x_i = scatter(idx0, attr0, abs(xh_i))
    for (int i = 1; i < 4; ++i)
        k_scatter<<<scb, 256, 0, stream>>>(hbuf + (size_t)(i - 1) * NF, sidx,
                                           sidx + ES_EDGES, sattr, xs + (size_t)i * NF,
                                           ES_EDGES, 1);

    hipMemcpyAsync(xacc, x, NF * sizeof(float), hipMemcpyDeviceToDevice, stream);

    for (int i = 0; i < 4; ++i) {
        // h = xs_i @ W_i   [N,64]@[64,256]
        k_gemm<0><<<dim3(N_NODES / 64, HF / 64), 256, 0, stream>>>(
            xs + (size_t)i * NF, gat_W + (size_t)i * F_DIM * HF, hbuf,
            nullptr, nullptr, N_NODES, F_DIM, HF);
        k_attn_coef<<<N_NODES * H_HEADS / 4, 256, 0, stream>>>(
            hbuf, gat_asrc + i * HF, gat_adst + i * HF, a_s, a_d);
        k_fill_u32<<<NH / 256, 256, 0, stream>>>(menc, 0x007FFFFFu, NH);  // enc(-inf)
        hipMemsetAsync(denom, 0, NH * sizeof(float), stream);
        hipMemsetAsync(gout, 0, 4 * NF * sizeof(float), stream);
        k_attn_max<<<E2H / 256, 256, 0, stream>>>(ei, a_s, a_d, menc);
        k_attn_exp<<<E2H / 256, 256, 0, stream>>>(ei, a_s, a_d, menc, exbuf, denom);
        k_attn_agg<<<E2H / 4, 256, 0, stream>>>(ei, hbuf, exbuf, denom, gout);
        // z = elu(gout + gat_b) @ mlp_W + mlp_b   [N,256]@[256,64]
        k_gemm<1><<<dim3(N_NODES / 64, 1), 256, 0, stream>>>(
            gout, mlp_W + (size_t)i * HF * F_DIM, zbuf,
            gat_b + i * HF, mlp_b + i * F_DIM, N_NODES, HF, F_DIM);
        hipMemsetAsync(sums, 0, 128 * sizeof(float), stream);
        k_colstats<<<64, 256, 0, stream>>>(zbuf, sums, sumsq);
        k_bn_acc<<<N_NODES * F_DIM / 256, 256, 0, stream>>>(
            zbuf, sums, sumsq, mlp_g + i * F_DIM, mlp_beta + i * F_DIM, xacc);
    }

    hipMemsetAsync(pooled, 0, G_GRAPHS * F_DIM * sizeof(float), stream);
    k_pool<<<64, 256, 0, stream>>>(xacc, batch, pooled);

    k_fc<<<(64 * 256) / 256, 256, 0, stream>>>(pooled, fc1_W, fc1_b, h1, 64, 64, 256);
    k_bn_small<<<1, 256, 0, stream>>>(h1, fc1_g, fc1_beta, 64, 256, 1, h1);
    k_fc<<<(64 * 128) / 256, 256, 0, stream>>>(h1, fc2_W, fc2_b, h2, 64, 256, 128);
    k_bn_small<<<1, 128, 0, stream>>>(h2, fc2_g, fc2_beta, 64, 128, 1, h2);
    k_fc<<<3, 256, 0, stream>>>(h2, fc3_W, fc3_b, f3, 64, 128, 10);
    k_bn_small<<<1, 64, 0, stream>>>(f3, fc3_g, fc3_beta, 64, 10, 0, (float*)d_out);
}

// Round 2
// 2384.450 us; speedup vs baseline: 1.5465x; 1.5465x over previous
//
#include <hip/hip_runtime.h>
#include <hip/hip_bf16.h>

#define N_NODES 32768
#define F_DIM 64
#define H_HEADS 4
#define HF 256
#define ES_EDGES 524288
#define EG_EDGES 524288
#define G_GRAPHS 64
#define NC_OUT 10
#define BN_EPS 1e-5f
#define NH (N_NODES * H_HEADS)

__device__ __forceinline__ float eluf(float x) { return x > 0.f ? x : expm1f(x); }
__device__ __forceinline__ float lreluf(float x) { return x > 0.f ? x : 0.2f * x; }

// ---------------- CSR build ----------------
__global__ void k_hist(const int* __restrict__ dst, int* __restrict__ deg, int E) {
    int t = blockIdx.x * 256 + threadIdx.x;
    if (t < E) atomicAdd(&deg[dst[t]], 1);
}

// exclusive scan of deg[0..32768) -> rp[0..32768], single block of 1024 threads
__global__ void k_scan(const int* __restrict__ deg, int* __restrict__ rp) {
    __shared__ int part[1024];
    int t = threadIdx.x;
    int base = t * 32;
    int loc[32];
    int s = 0;
#pragma unroll
    for (int i = 0; i < 32; ++i) { loc[i] = s; s += deg[base + i]; }
    part[t] = s;
    __syncthreads();
    for (int off = 1; off < 1024; off <<= 1) {
        int v = (t >= off) ? part[t - off] : 0;
        __syncthreads();
        part[t] += v;
        __syncthreads();
    }
    int pref = (t == 0) ? 0 : part[t - 1];
#pragma unroll
    for (int i = 0; i < 32; ++i) rp[base + i] = pref + loc[i];
    if (t == 1023) rp[32768] = part[1023];
}

__global__ void k_fillcsr(const int* __restrict__ src, const int* __restrict__ dst,
                          const float* __restrict__ attr, int* __restrict__ cursor,
                          int* __restrict__ col, float* __restrict__ aval, int E) {
    int t = blockIdx.x * 256 + threadIdx.x;
    if (t >= E) return;
    int p = atomicAdd(&cursor[dst[t]], 1);
    col[p] = src[t];
    if (aval) aval[p] = attr[t];
}

// ---------------- scatter pass as CSR gather ----------------
// out[d,f] = sum_j aval[j] * (abs?) x[col[j], f]; one wave per node, lane=f
template <int DO_ABS>
__global__ void k_sgather(const float* __restrict__ x, const int* __restrict__ rp,
                          const int* __restrict__ col, const float* __restrict__ aval,
                          float* __restrict__ out) {
    int t = blockIdx.x * 256 + threadIdx.x;
    int d = t >> 6, f = t & 63;
    int j0 = rp[d], j1 = rp[d + 1];
    float acc = 0.f;
    for (int j = j0; j < j1; ++j) {
        float v = x[(size_t)col[j] * 64 + f];
        if (DO_ABS) v = fabsf(v);
        acc += aval[j] * v;
    }
    out[t] = acc;
}

// ---------------- GAT ----------------
// a_s[n,h] = sum_f h[n,h,f]*asrc[h,f]; same for a_d. One wave per (n,h).
__global__ void k_attn_coef(const float* __restrict__ h, const float* __restrict__ asrc,
                            const float* __restrict__ adst, float* __restrict__ a_s,
                            float* __restrict__ a_d) {
    int t = blockIdx.x * 256 + threadIdx.x;
    int w = t >> 6, lane = t & 63;
    int hd = w & 3;
    float hv = h[(size_t)w * 64 + lane];
    float s1 = hv * asrc[hd * 64 + lane];
    float s2 = hv * adst[hd * 64 + lane];
    for (int off = 32; off; off >>= 1) {
        s1 += __shfl_xor(s1, off);
        s2 += __shfl_xor(s2, off);
    }
    if (lane == 0) { a_s[w] = s1; a_d[w] = s2; }
}

// Fused softmax + aggregation. One wave per (dst,head), lane = feature.
// Self-loop handled implicitly. gout[d,hd,f] = sum_j alpha_j * h[src_j,hd,f]
__global__ void k_gat_fused(const int* __restrict__ rp, const int* __restrict__ col,
                            const float* __restrict__ a_s, const float* __restrict__ a_d,
                            const float* __restrict__ hmat, float* __restrict__ gout) {
    int t = blockIdx.x * 256 + threadIdx.x;
    int w = t >> 6, lane = t & 63;
    int d = w >> 2, hd = w & 3;
    int j0 = rp[d], j1 = rp[d + 1];
    float a_dd = a_d[d * 4 + hd];
    float e_self = lreluf(a_s[d * 4 + hd] + a_dd);
    // pass 1: segment max (lanes stripe edges)
    float m = e_self;
    for (int j = j0 + lane; j < j1; j += 64)
        m = fmaxf(m, lreluf(a_s[col[j] * 4 + hd] + a_dd));
    for (int off = 32; off; off >>= 1) m = fmaxf(m, __shfl_xor(m, off));
    // pass 2: unnormalized accumulate, divide once
    float denom = expf(e_self - m);
    float acc = denom * hmat[(size_t)d * 256 + hd * 64 + lane];
    for (int j = j0; j < j1; ++j) {
        int s = col[j];
        float ex = expf(lreluf(a_s[s * 4 + hd] + a_dd) - m);
        acc += ex * hmat[(size_t)s * 256 + hd * 64 + lane];
        denom += ex;
    }
    gout[(size_t)d * 256 + hd * 64 + lane] = acc / denom;
}

// ---------------- GEMM ----------------
// C[M,Nc] = op(A)[M,K] @ B[K,Nc] (+cbias). TRANSFORM=1: op(A)=elu(A+abias[k]).
template <int TRANSFORM>
__global__ void k_gemm(const float* __restrict__ A, const float* __restrict__ B,
                       float* __restrict__ C, const float* __restrict__ abias,
                       const float* __restrict__ cbias, int M, int K, int Nc) {
    __shared__ float As[16][68];
    __shared__ float Bs[16][64];
    int bm = blockIdx.x * 64;
    int bn = blockIdx.y * 64;
    int tid = threadIdx.x;
    int tx = tid & 15, ty = tid >> 4;
    float acc[4][4] = {};
    for (int k0 = 0; k0 < K; k0 += 16) {
        {
            int m = tid >> 2, k4 = (tid & 3) * 4;
            float4 v = *(const float4*)&A[(size_t)(bm + m) * K + k0 + k4];
            if (TRANSFORM == 1) {
                v.x = eluf(v.x + abias[k0 + k4 + 0]);
                v.y = eluf(v.y + abias[k0 + k4 + 1]);
                v.z = eluf(v.z + abias[k0 + k4 + 2]);
                v.w = eluf(v.w + abias[k0 + k4 + 3]);
            }
            As[k4 + 0][m] = v.x; As[k4 + 1][m] = v.y;
            As[k4 + 2][m] = v.z; As[k4 + 3][m] = v.w;
        }
        {
            int k = tid >> 4, n4 = (tid & 15) * 4;
            *(float4*)&Bs[k][n4] = *(const float4*)&B[(size_t)(k0 + k) * Nc + bn + n4];
        }
        __syncthreads();
#pragma unroll
        for (int k = 0; k < 16; ++k) {
            float4 a = *(const float4*)&As[k][ty * 4];
            float4 b = *(const float4*)&Bs[k][tx * 4];
            acc[0][0] += a.x * b.x; acc[0][1] += a.x * b.y; acc[0][2] += a.x * b.z; acc[0][3] += a.x * b.w;
            acc[1][0] += a.y * b.x; acc[1][1] += a.y * b.y; acc[1][2] += a.y * b.z; acc[1][3] += a.y * b.w;
            acc[2][0] += a.z * b.x; acc[2][1] += a.z * b.y; acc[2][2] += a.z * b.z; acc[2][3] += a.z * b.w;
            acc[3][0] += a.w * b.x; acc[3][1] += a.w * b.y; acc[3][2] += a.w * b.z; acc[3][3] += a.w * b.w;
        }
        __syncthreads();
    }
#pragma unroll
    for (int i = 0; i < 4; ++i)
#pragma unroll
        for (int j = 0; j < 4; ++j) {
            float cb = cbias ? cbias[bn + tx * 4 + j] : 0.f;
            C[(size_t)(bm + ty * 4 + i) * Nc + bn + tx * 4 + j] = acc[i][j] + cb;
        }
}

// ---------------- BN / pool / head ----------------
__global__ void k_colstats(const float* __restrict__ z, float* __restrict__ sums,
                           float* __restrict__ sumsq) {
    int col = threadIdx.x & 63, rg = threadIdx.x >> 6;
    int base = blockIdx.x * 512;
    float s = 0.f, sq = 0.f;
    for (int r = base + rg; r < base + 512; r += 4) {
        float v = z[(size_t)r * 64 + col];
        s += v; sq += v * v;
    }
    __shared__ float ls[256], lq[256];
    ls[threadIdx.x] = s; lq[threadIdx.x] = sq;
    __syncthreads();
    if (threadIdx.x < 64) {
        int c = threadIdx.x;
        float ts = ls[c] + ls[c + 64] + ls[c + 128] + ls[c + 192];
        float tq = lq[c] + lq[c + 64] + lq[c + 128] + lq[c + 192];
        unsafeAtomicAdd(&sums[c], ts);
        unsafeAtomicAdd(&sumsq[c], tq);
    }
}

__global__ void k_bn_acc(const float* __restrict__ z, const float* __restrict__ sums,
                         const float* __restrict__ sumsq, const float* __restrict__ g,
                         const float* __restrict__ beta, float* __restrict__ xacc) {
    int t = blockIdx.x * 256 + threadIdx.x;
    int col = t & 63;
    const float invN = 1.f / (float)N_NODES;
    float mu = sums[col] * invN;
    float var = sumsq[col] * invN - mu * mu;
    float sc = g[col] * rsqrtf(var + BN_EPS);
    xacc[t] += (z[t] - mu) * sc + beta[col];
}

__global__ void k_pool(const float* __restrict__ xa, const int* __restrict__ batch,
                       float* __restrict__ pooled) {
    int col = threadIdx.x & 63, rg = threadIdx.x >> 6;
    int r0 = blockIdx.x * 512 + rg * 128;
    int cur = -1;
    float acc = 0.f;
    for (int r = r0; r < r0 + 128; ++r) {
        int g = batch[r];
        if (g != cur) {
            if (cur >= 0) unsafeAtomicAdd(&pooled[cur * 64 + col], acc);
            cur = g; acc = 0.f;
        }
        acc += xa[(size_t)r * 64 + col];
    }
    if (cur >= 0) unsafeAtomicAdd(&pooled[cur * 64 + col], acc);
}

__global__ void k_fc(const float* __restrict__ A, const float* __restrict__ B,
                     const float* __restrict__ bias, float* __restrict__ C,
                     int M, int K, int Nc) {
    int t = blockIdx.x * 256 + threadIdx.x;
    if (t >= M * Nc) return;
    int m = t / Nc, n = t % Nc;
    float s = bias[n];
    for (int k = 0; k < K; ++k) s += A[m * K + k] * B[k * Nc + n];
    C[t] = s;
}

__global__ void k_bn_small(const float* __restrict__ Y, const float* __restrict__ g,
                           const float* __restrict__ beta, int M, int C, int relu,
                           float* __restrict__ out) {
    int c = threadIdx.x;
    if (c >= C) return;
    float s = 0.f, sq = 0.f;
    for (int m = 0; m < M; ++m) {
        float v = Y[m * C + c];
        s += v; sq += v * v;
    }
    float mu = s / (float)M;
    float var = sq / (float)M - mu * mu;
    float sc = g[c] * rsqrtf(var + BN_EPS);
    for (int m = 0; m < M; ++m) {
        float v = (Y[m * C + c] - mu) * sc + beta[c];
        if (relu) v = fmaxf(v, 0.f);
        out[m * C + c] = v;
    }
}

extern "C" void kernel_launch(void* const* d_in, const int* in_sizes, int n_in,
                              void* d_out, int out_size, void* d_ws, size_t ws_size,
                              hipStream_t stream) {
    const float* x        = (const float*)d_in[0];
    const int*   ei       = (const int*)d_in[1];
    const int*   batch    = (const int*)d_in[2];
    const int*   sidx     = (const int*)d_in[3];
    const float* sattr    = (const float*)d_in[4];
    const float* gat_W    = (const float*)d_in[5];
    const float* gat_asrc = (const float*)d_in[6];
    const float* gat_adst = (const float*)d_in[7];
    const float* gat_b    = (const float*)d_in[8];
    const float* mlp_W    = (const float*)d_in[9];
    const float* mlp_b    = (const float*)d_in[10];
    const float* mlp_g    = (const float*)d_in[11];
    const float* mlp_beta = (const float*)d_in[12];
    const float* fc1_W    = (const float*)d_in[13];
    const float* fc1_b    = (const float*)d_in[14];
    const float* fc1_g    = (const float*)d_in[15];
    const float* fc1_beta = (const float*)d_in[16];
    const float* fc2_W    = (const float*)d_in[17];
    const float* fc2_b    = (const float*)d_in[18];
    const float* fc2_g    = (const float*)d_in[19];
    const float* fc2_beta = (const float*)d_in[20];
    const float* fc3_W    = (const float*)d_in[21];
    const float* fc3_b    = (const float*)d_in[22];
    const float* fc3_g    = (const float*)d_in[23];
    const float* fc3_beta = (const float*)d_in[24];

    const size_t NF = (size_t)N_NODES * F_DIM;
    float* p = (float*)d_ws;
    float* xs    = p; p += 4 * NF;
    float* hbuf  = p; p += 4 * NF;   // h matrix [N,256]; also xh staging (3*NF)
    float* gout  = p; p += 4 * NF;
    float* zbuf  = p; p += NF;
    float* xacc  = p; p += NF;
    float* a_s   = p; p += NH;
    float* a_d   = p; p += NH;
    float* sums  = p; p += 64;
    float* sumsq = p; p += 64;
    float* pooled= p; p += G_GRAPHS * F_DIM;
    float* h1    = p; p += 64 * 256;
    float* h2    = p; p += 64 * 128;
    float* f3    = p; p += 64 * NC_OUT;
    int* ip = (int*)p;
    int* rp_g  = ip; ip += N_NODES + 1;
    int* col_g = ip; ip += EG_EDGES;
    int* rp_s[4]; int* col_s[4]; float* attr_s[4];
    for (int i = 0; i < 4; ++i) {
        rp_s[i] = ip;   ip += N_NODES + 1;
        col_s[i] = ip;  ip += ES_EDGES;
        attr_s[i] = (float*)ip; ip += ES_EDGES;
    }
    int* deg = ip; ip += N_NODES;   // scratch: histogram, then cursor

    const int EB = (ES_EDGES + 255) / 256;

    // ---- build CSRs (dst-sorted) ----
    auto build = [&](const int* src, const int* dst, const float* attr,
                     int* rp, int* col, float* aval) {
        hipMemsetAsync(deg, 0, N_NODES * sizeof(int), stream);
        k_hist<<<EB, 256, 0, stream>>>(dst, deg, ES_EDGES);
        k_scan<<<1, 1024, 0, stream>>>(deg, rp);
        hipMemcpyAsync(deg, rp, N_NODES * sizeof(int), hipMemcpyDeviceToDevice, stream);
        k_fillcsr<<<EB, 256, 0, stream>>>(src, dst, attr, deg, col, aval, ES_EDGES);
    };
    build(ei, ei + EG_EDGES, nullptr, rp_g, col_g, nullptr);
    for (int i = 0; i < 4; ++i)
        build(sidx + (size_t)i * 2 * ES_EDGES, sidx + (size_t)i * 2 * ES_EDGES + ES_EDGES,
              sattr + (size_t)i * ES_EDGES, rp_s[i], col_s[i], attr_s[i]);

    // ---- scatter passes as gathers ----
    const int GB = N_NODES * 64 / 256;
    k_sgather<0><<<GB, 256, 0, stream>>>(x, rp_s[0], col_s[0], attr_s[0], xs);
    for (int i = 1; i < 4; ++i)
        k_sgather<0><<<GB, 256, 0, stream>>>(x, rp_s[i], col_s[i], attr_s[i],
                                             hbuf + (size_t)(i - 1) * NF);
    for (int i = 1; i < 4; ++i)
        k_sgather<1><<<GB, 256, 0, stream>>>(hbuf + (size_t)(i - 1) * NF, rp_s[0],
                                             col_s[0], attr_s[0], xs + (size_t)i * NF);

    hipMemcpyAsync(xacc, x, NF * sizeof(float), hipMemcpyDeviceToDevice, stream);

    // ---- 4 GAT + MLP + BN layers ----
    for (int i = 0; i < 4; ++i) {
        k_gemm<0><<<dim3(N_NODES / 64, HF / 64), 256, 0, stream>>>(
            xs + (size_t)i * NF, gat_W + (size_t)i * F_DIM * HF, hbuf,
            nullptr, nullptr, N_NODES, F_DIM, HF);
        k_attn_coef<<<NH / 4, 256, 0, stream>>>(
            hbuf, gat_asrc + i * HF, gat_adst + i * HF, a_s, a_d);
        k_gat_fused<<<NH * 64 / 256, 256, 0, stream>>>(rp_g, col_g, a_s, a_d, hbuf, gout);
        k_gemm<1><<<dim3(N_NODES / 64, 1), 256, 0, stream>>>(
            gout, mlp_W + (size_t)i * HF * F_DIM, zbuf,
            gat_b + i * HF, mlp_b + i * F_DIM, N_NODES, HF, F_DIM);
        hipMemsetAsync(sums, 0, 128 * sizeof(float), stream);
        k_colstats<<<64, 256, 0, stream>>>(zbuf, sums, sumsq);
        k_bn_acc<<<N_NODES * F_DIM / 256, 256, 0, stream>>>(
            zbuf, sums, sumsq, mlp_g + i * F_DIM, mlp_beta + i * F_DIM, xacc);
    }

    // ---- pool + FC head ----
    hipMemsetAsync(pooled, 0, G_GRAPHS * F_DIM * sizeof(float), stream);
    k_pool<<<64, 256, 0, stream>>>(xacc, batch, pooled);

    k_fc<<<(64 * 256) / 256, 256, 0, stream>>>(pooled, fc1_W, fc1_b, h1, 64, 64, 256);
    k_bn_small<<<1, 256, 0, stream>>>(h1, fc1_g, fc1_beta, 64, 256, 1, h1);
    k_fc<<<(64 * 128) / 256, 256, 0, stream>>>(h1, fc2_W, fc2_b, h2, 64, 256, 128);
    k_bn_small<<<1, 128, 0, stream>>>(h2, fc2_g, fc2_beta, 64, 128, 1, h2);
    k_fc<<<3, 256, 0, stream>>>(h2, fc3_W, fc3_b, f3, 64, 128, 10);
    k_bn_small<<<1, 64, 0, stream>>>(f3, fc3_g, fc3_beta, 64, 10, 0, (float*)d_out);
}

// Round 4
// 1638.599 us; speedup vs baseline: 2.2505x; 1.4552x over previous
//
#include <hip/hip_runtime.h>
#include <hip/hip_bf16.h>

#define N_NODES 32768
#define F_DIM 64
#define H_HEADS 4
#define HF 256
#define ES_EDGES 524288
#define EG_EDGES 524288
#define G_GRAPHS 64
#define NC_OUT 10
#define BN_EPS 1e-5f
#define NH (N_NODES * H_HEADS)
#define NF_ELEMS (N_NODES * F_DIM)

__device__ __forceinline__ float eluf(float x) { return x > 0.f ? x : expm1f(x); }
__device__ __forceinline__ float lreluf(float x) { return x > 0.f ? x : 0.2f * x; }

struct P5i { const int* p[5]; };
struct P5f { const float* p[5]; };

// ---------------- batched CSR build (5 graphs) ----------------
__global__ void k_hist5(P5i dst, int* __restrict__ deg, int E) {
    int t = blockIdx.x * 256 + threadIdx.x;
    int g = blockIdx.y;
    if (t < E) atomicAdd(&deg[g * N_NODES + dst.p[g][t]], 1);
}

// per-graph exclusive scan; writes rp[g] and cursor cur[g] (cur may alias deg:
// each thread reads only its own 32 deg entries before any write)
__global__ void k_scan5(const int* __restrict__ deg, int* __restrict__ rp,
                        int* __restrict__ cur) {
    int g = blockIdx.x;
    deg += g * N_NODES;
    rp += g * (N_NODES + 1);
    cur += g * N_NODES;
    __shared__ int part[1024];
    int t = threadIdx.x;
    int base = t * 32;
    int loc[32];
    int s = 0;
#pragma unroll
    for (int i = 0; i < 32; ++i) { loc[i] = s; s += deg[base + i]; }
    part[t] = s;
    __syncthreads();
    for (int off = 1; off < 1024; off <<= 1) {
        int v = (t >= off) ? part[t - off] : 0;
        __syncthreads();
        part[t] += v;
        __syncthreads();
    }
    int pref = (t == 0) ? 0 : part[t - 1];
#pragma unroll
    for (int i = 0; i < 32; ++i) {
        rp[base + i] = pref + loc[i];
        cur[base + i] = pref + loc[i];
    }
    if (t == 1023) rp[32768] = part[1023];
}

// avalb holds only the 4 scatter graphs (batched graph g -> slot g-1)
__global__ void k_fill5(P5i src, P5i dst, P5f attr, int* __restrict__ cur,
                        int* __restrict__ colb, float* __restrict__ avalb, int E) {
    int t = blockIdx.x * 256 + threadIdx.x;
    int g = blockIdx.y;
    if (t >= E) return;
    int p = atomicAdd(&cur[g * N_NODES + dst.p[g][t]], 1);
    colb[(size_t)g * E + p] = src.p[g][t];
    const float* a = attr.p[g];
    if (a) avalb[(size_t)(g - 1) * E + p] = a[t];
}

// ---------------- xh gathers ----------------
// output slot g=0..2 is xh_{g+1}, which uses scatter_idx[g+1] = batched graph g+2
__global__ void k_sgather3(const float* __restrict__ x, const int* __restrict__ rpb,
                           const int* __restrict__ colb, const float* __restrict__ avalb,
                           float* __restrict__ out) {
    int g = blockIdx.y;
    const int* rp = rpb + (g + 2) * (N_NODES + 1);
    const int* col = colb + (size_t)(g + 2) * ES_EDGES;
    const float* av = avalb + (size_t)(g + 1) * ES_EDGES;
    float* o = out + (size_t)g * NF_ELEMS;
    int t = blockIdx.x * 256 + threadIdx.x;
    int d = t >> 6, f = t & 63;
    int j0 = rp[d], j1 = rp[d + 1];
    float acc = 0.f;
    int j = j0;
    for (; j + 4 <= j1; j += 4) {
        int s0 = col[j], s1 = col[j + 1], s2 = col[j + 2], s3 = col[j + 3];
        float w0 = av[j], w1 = av[j + 1], w2 = av[j + 2], w3 = av[j + 3];
        float v0 = x[(size_t)s0 * 64 + f], v1 = x[(size_t)s1 * 64 + f];
        float v2 = x[(size_t)s2 * 64 + f], v3 = x[(size_t)s3 * 64 + f];
        acc += w0 * v0 + w1 * v1 + w2 * v2 + w3 * v3;
    }
    for (; j < j1; ++j) acc += av[j] * x[(size_t)col[j] * 64 + f];
    o[t] = acc;
}

// ---------------- fused CSR0 gathers: x0..x3 in one pass (graph 1) ------------
__global__ void k_sgather_quad(const float* __restrict__ x, const float* __restrict__ xh,
                               const int* __restrict__ rp, const int* __restrict__ col,
                               const float* __restrict__ av, float* __restrict__ xs) {
    int t = blockIdx.x * 256 + threadIdx.x;
    int d = t >> 6, f = t & 63;
    int j0 = rp[d], j1 = rp[d + 1];
    const float* x1 = xh;
    const float* x2 = xh + NF_ELEMS;
    const float* x3 = xh + 2 * (size_t)NF_ELEMS;
    float a0 = 0.f, a1 = 0.f, a2 = 0.f, a3 = 0.f;
    int j = j0;
    for (; j + 2 <= j1; j += 2) {
        int s0 = col[j], s1 = col[j + 1];
        float w0 = av[j], w1 = av[j + 1];
        size_t b0 = (size_t)s0 * 64 + f, b1 = (size_t)s1 * 64 + f;
        a0 += w0 * x[b0] + w1 * x[b1];
        a1 += w0 * fabsf(x1[b0]) + w1 * fabsf(x1[b1]);
        a2 += w0 * fabsf(x2[b0]) + w1 * fabsf(x2[b1]);
        a3 += w0 * fabsf(x3[b0]) + w1 * fabsf(x3[b1]);
    }
    for (; j < j1; ++j) {
        size_t b = (size_t)col[j] * 64 + f;
        float w = av[j];
        a0 += w * x[b];
        a1 += w * fabsf(x1[b]);
        a2 += w * fabsf(x2[b]);
        a3 += w * fabsf(x3[b]);
    }
    xs[t] = a0;
    xs[NF_ELEMS + t] = a1;
    xs[2 * (size_t)NF_ELEMS + t] = a2;
    xs[3 * (size_t)NF_ELEMS + t] = a3;
}

// ---------------- GAT ----------------
__global__ void k_attn_coef(const float* __restrict__ h, const float* __restrict__ asrc,
                            const float* __restrict__ adst, float* __restrict__ a_s,
                            float* __restrict__ a_d) {
    int t = blockIdx.x * 256 + threadIdx.x;
    int w = t >> 6, lane = t & 63;
    int hd = w & 3;
    float hv = h[(size_t)w * 64 + lane];
    float s1 = hv * asrc[hd * 64 + lane];
    float s2 = hv * adst[hd * 64 + lane];
    for (int off = 32; off; off >>= 1) {
        s1 += __shfl_xor(s1, off);
        s2 += __shfl_xor(s2, off);
    }
    if (lane == 0) { a_s[w] = s1; a_d[w] = s2; }
}

// fused softmax + aggregation; one wave per (dst,head), lane = feature
__global__ void k_gat_fused(const int* __restrict__ rp, const int* __restrict__ col,
                            const float* __restrict__ a_s, const float* __restrict__ a_d,
                            const float* __restrict__ hmat, float* __restrict__ gout) {
    int t = blockIdx.x * 256 + threadIdx.x;
    int w = t >> 6, lane = t & 63;
    int d = w >> 2, hd = w & 3;
    int j0 = rp[d], j1 = rp[d + 1];
    float a_dd = a_d[d * 4 + hd];
    float e_self = lreluf(a_s[d * 4 + hd] + a_dd);
    // pass 1: segment max, lanes stripe edges
    float m = e_self;
    for (int j = j0 + lane; j < j1; j += 64)
        m = fmaxf(m, lreluf(a_s[col[j] * 4 + hd] + a_dd));
    for (int off = 32; off; off >>= 1) m = fmaxf(m, __shfl_xor(m, off));
    // pass 2: unrolled accumulate
    float denom = __expf(e_self - m);
    float acc = denom * hmat[(size_t)d * 256 + hd * 64 + lane];
    int j = j0;
    for (; j + 4 <= j1; j += 4) {
        int s0 = col[j], s1 = col[j + 1], s2 = col[j + 2], s3 = col[j + 3];
        float e0 = __expf(lreluf(a_s[s0 * 4 + hd] + a_dd) - m);
        float e1 = __expf(lreluf(a_s[s1 * 4 + hd] + a_dd) - m);
        float e2 = __expf(lreluf(a_s[s2 * 4 + hd] + a_dd) - m);
        float e3 = __expf(lreluf(a_s[s3 * 4 + hd] + a_dd) - m);
        float h0 = hmat[(size_t)s0 * 256 + hd * 64 + lane];
        float h1 = hmat[(size_t)s1 * 256 + hd * 64 + lane];
        float h2 = hmat[(size_t)s2 * 256 + hd * 64 + lane];
        float h3 = hmat[(size_t)s3 * 256 + hd * 64 + lane];
        acc += e0 * h0 + e1 * h1 + e2 * h2 + e3 * h3;
        denom += e0 + e1 + e2 + e3;
    }
    for (; j < j1; ++j) {
        int s = col[j];
        float ex = __expf(lreluf(a_s[s * 4 + hd] + a_dd) - m);
        acc += ex * hmat[(size_t)s * 256 + hd * 64 + lane];
        denom += ex;
    }
    gout[(size_t)d * 256 + hd * 64 + lane] = acc / denom;
}

// ---------------- GEMM ----------------
template <int TRANSFORM>
__global__ void k_gemm(const float* __restrict__ A, const float* __restrict__ B,
                       float* __restrict__ C, const float* __restrict__ abias,
                       const float* __restrict__ cbias, int M, int K, int Nc) {
    __shared__ float As[16][68];
    __shared__ float Bs[16][64];
    int bm = blockIdx.x * 64;
    int bn = blockIdx.y * 64;
    int tid = threadIdx.x;
    int tx = tid & 15, ty = tid >> 4;
    float acc[4][4] = {};
    for (int k0 = 0; k0 < K; k0 += 16) {
        {
            int m = tid >> 2, k4 = (tid & 3) * 4;
            float4 v = *(const float4*)&A[(size_t)(bm + m) * K + k0 + k4];
            if (TRANSFORM == 1) {
                v.x = eluf(v.x + abias[k0 + k4 + 0]);
                v.y = eluf(v.y + abias[k0 + k4 + 1]);
                v.z = eluf(v.z + abias[k0 + k4 + 2]);
                v.w = eluf(v.w + abias[k0 + k4 + 3]);
            }
            As[k4 + 0][m] = v.x; As[k4 + 1][m] = v.y;
            As[k4 + 2][m] = v.z; As[k4 + 3][m] = v.w;
        }
        {
            int k = tid >> 4, n4 = (tid & 15) * 4;
            *(float4*)&Bs[k][n4] = *(const float4*)&B[(size_t)(k0 + k) * Nc + bn + n4];
        }
        __syncthreads();
#pragma unroll
        for (int k = 0; k < 16; ++k) {
            float4 a = *(const float4*)&As[k][ty * 4];
            float4 b = *(const float4*)&Bs[k][tx * 4];
            acc[0][0] += a.x * b.x; acc[0][1] += a.x * b.y; acc[0][2] += a.x * b.z; acc[0][3] += a.x * b.w;
            acc[1][0] += a.y * b.x; acc[1][1] += a.y * b.y; acc[1][2] += a.y * b.z; acc[1][3] += a.y * b.w;
            acc[2][0] += a.z * b.x; acc[2][1] += a.z * b.y; acc[2][2] += a.z * b.z; acc[2][3] += a.z * b.w;
            acc[3][0] += a.w * b.x; acc[3][1] += a.w * b.y; acc[3][2] += a.w * b.z; acc[3][3] += a.w * b.w;
        }
        __syncthreads();
    }
#pragma unroll
    for (int i = 0; i < 4; ++i)
#pragma unroll
        for (int j = 0; j < 4; ++j) {
            float cb = cbias ? cbias[bn + tx * 4 + j] : 0.f;
            C[(size_t)(bm + ty * 4 + i) * Nc + bn + tx * 4 + j] = acc[i][j] + cb;
        }
}

// ---------------- BN / pool / head ----------------
__global__ void k_colstats(const float* __restrict__ z, float* __restrict__ sums,
                           float* __restrict__ sumsq) {
    int col = threadIdx.x & 63, rg = threadIdx.x >> 6;
    int base = blockIdx.x * 512;
    float s = 0.f, sq = 0.f;
    for (int r = base + rg; r < base + 512; r += 4) {
        float v = z[(size_t)r * 64 + col];
        s += v; sq += v * v;
    }
    __shared__ float ls[256], lq[256];
    ls[threadIdx.x] = s; lq[threadIdx.x] = sq;
    __syncthreads();
    if (threadIdx.x < 64) {
        int c = threadIdx.x;
        float ts = ls[c] + ls[c + 64] + ls[c + 128] + ls[c + 192];
        float tq = lq[c] + lq[c + 64] + lq[c + 128] + lq[c + 192];
        unsafeAtomicAdd(&sums[c], ts);
        unsafeAtomicAdd(&sumsq[c], tq);
    }
}

__global__ void k_bn_acc(const float* __restrict__ z, const float* __restrict__ sums,
                         const float* __restrict__ sumsq, const float* __restrict__ g,
                         const float* __restrict__ beta, float* __restrict__ xacc) {
    int t = blockIdx.x * 256 + threadIdx.x;
    int col = t & 63;
    const float invN = 1.f / (float)N_NODES;
    float mu = sums[col] * invN;
    float var = sumsq[col] * invN - mu * mu;
    float sc = g[col] * rsqrtf(var + BN_EPS);
    xacc[t] += (z[t] - mu) * sc + beta[col];
}

__global__ void k_pool(const float* __restrict__ xa, const int* __restrict__ batch,
                       float* __restrict__ pooled) {
    int col = threadIdx.x & 63, rg = threadIdx.x >> 6;
    int r0 = blockIdx.x * 512 + rg * 128;
    int cur = -1;
    float acc = 0.f;
    for (int r = r0; r < r0 + 128; ++r) {
        int g = batch[r];
        if (g != cur) {
            if (cur >= 0) unsafeAtomicAdd(&pooled[cur * 64 + col], acc);
            cur = g; acc = 0.f;
        }
        acc += xa[(size_t)r * 64 + col];
    }
    if (cur >= 0) unsafeAtomicAdd(&pooled[cur * 64 + col], acc);
}

__global__ void k_fc(const float* __restrict__ A, const float* __restrict__ B,
                     const float* __restrict__ bias, float* __restrict__ C,
                     int M, int K, int Nc) {
    int t = blockIdx.x * 256 + threadIdx.x;
    if (t >= M * Nc) return;
    int m = t / Nc, n = t % Nc;
    float s = bias[n];
    for (int k = 0; k < K; ++k) s += A[m * K + k] * B[k * Nc + n];
    C[t] = s;
}

__global__ void k_bn_small(const float* __restrict__ Y, const float* __restrict__ g,
                           const float* __restrict__ beta, int M, int C, int relu,
                           float* __restrict__ out) {
    int c = threadIdx.x;
    if (c >= C) return;
    float s = 0.f, sq = 0.f;
    for (int m = 0; m < M; ++m) {
        float v = Y[m * C + c];
        s += v; sq += v * v;
    }
    float mu = s / (float)M;
    float var = sq / (float)M - mu * mu;
    float sc = g[c] * rsqrtf(var + BN_EPS);
    for (int m = 0; m < M; ++m) {
        float v = (Y[m * C + c] - mu) * sc + beta[c];
        if (relu) v = fmaxf(v, 0.f);
        out[m * C + c] = v;
    }
}

extern "C" void kernel_launch(void* const* d_in, const int* in_sizes, int n_in,
                              void* d_out, int out_size, void* d_ws, size_t ws_size,
                              hipStream_t stream) {
    const float* x        = (const float*)d_in[0];
    const int*   ei       = (const int*)d_in[1];
    const int*   batch    = (const int*)d_in[2];
    const int*   sidx     = (const int*)d_in[3];
    const float* sattr    = (const float*)d_in[4];
    const float* gat_W    = (const float*)d_in[5];
    const float* gat_asrc = (const float*)d_in[6];
    const float* gat_adst = (const float*)d_in[7];
    const float* gat_b    = (const float*)d_in[8];
    const float* mlp_W    = (const float*)d_in[9];
    const float* mlp_b    = (const float*)d_in[10];
    const float* mlp_g    = (const float*)d_in[11];
    const float* mlp_beta = (const float*)d_in[12];
    const float* fc1_W    = (const float*)d_in[13];
    const float* fc1_b    = (const float*)d_in[14];
    const float* fc1_g    = (const float*)d_in[15];
    const float* fc1_beta = (const float*)d_in[16];
    const float* fc2_W    = (const float*)d_in[17];
    const float* fc2_b    = (const float*)d_in[18];
    const float* fc2_g    = (const float*)d_in[19];
    const float* fc2_beta = (const float*)d_in[20];
    const float* fc3_W    = (const float*)d_in[21];
    const float* fc3_b    = (const float*)d_in[22];
    const float* fc3_g    = (const float*)d_in[23];
    const float* fc3_beta = (const float*)d_in[24];

    const size_t NF = (size_t)NF_ELEMS;
    float* p = (float*)d_ws;
    float* xs    = p; p += 4 * NF;
    float* hbuf  = p; p += 4 * NF;   // xh staging (3*NF) then h matrix [N,256]
    float* gout  = p; p += 4 * NF;
    float* zbuf  = p; p += NF;
    float* xacc  = p; p += NF;
    float* a_s   = p; p += NH;
    float* a_d   = p; p += NH;
    float* sums  = p; p += 64;
    float* sumsq = p; p += 64;
    float* pooled= p; p += G_GRAPHS * F_DIM;
    float* h1    = p; p += 64 * 256;
    float* h2    = p; p += 64 * 128;
    float* f3    = p; p += 64 * NC_OUT;
    float* avalb = p; p += 4 * (size_t)ES_EDGES;   // scatter graphs only
    int* ip = (int*)p;
    int* rpb  = ip; ip += 5 * (N_NODES + 1);
    int* colb = ip; ip += 5 * (size_t)ES_EDGES;
    int* deg  = ip; ip += 5 * N_NODES;             // doubles as fill cursor

    const int EB = (ES_EDGES + 255) / 256;
    const int GB = N_NODES * 64 / 256;

    // ---- batched CSR build: g=0 is GAT graph, g=1..4 are scatter_idx[0..3] ----
    P5i srcs, dsts; P5f attrs;
    srcs.p[0] = ei;              dsts.p[0] = ei + EG_EDGES;          attrs.p[0] = nullptr;
    for (int i = 0; i < 4; ++i) {
        srcs.p[i + 1]  = sidx + (size_t)i * 2 * ES_EDGES;
        dsts.p[i + 1]  = sidx + (size_t)i * 2 * ES_EDGES + ES_EDGES;
        attrs.p[i + 1] = sattr + (size_t)i * ES_EDGES;
    }
    hipMemsetAsync(deg, 0, 5 * N_NODES * sizeof(int), stream);
    k_hist5<<<dim3(EB, 5), 256, 0, stream>>>(dsts, deg, ES_EDGES);
    k_scan5<<<5, 1024, 0, stream>>>(deg, rpb, deg);
    k_fill5<<<dim3(EB, 5), 256, 0, stream>>>(srcs, dsts, attrs, deg, colb, avalb, ES_EDGES);

    // ---- scatter passes as gathers ----
    k_sgather3<<<dim3(GB, 3), 256, 0, stream>>>(x, rpb, colb, avalb, hbuf);
    k_sgather_quad<<<GB, 256, 0, stream>>>(
        x, hbuf, rpb + (N_NODES + 1), colb + ES_EDGES, avalb, xs);

    hipMemcpyAsync(xacc, x, NF * sizeof(float), hipMemcpyDeviceToDevice, stream);

    // ---- 4 GAT + MLP + BN layers ----
    for (int i = 0; i < 4; ++i) {
        k_gemm<0><<<dim3(N_NODES / 64, HF / 64), 256, 0, stream>>>(
            xs + (size_t)i * NF, gat_W + (size_t)i * F_DIM * HF, hbuf,
            nullptr, nullptr, N_NODES, F_DIM, HF);
        k_attn_coef<<<NH / 4, 256, 0, stream>>>(
            hbuf, gat_asrc + i * HF, gat_adst + i * HF, a_s, a_d);
        k_gat_fused<<<NH * 64 / 256, 256, 0, stream>>>(rpb, colb, a_s, a_d, hbuf, gout);
        k_gemm<1><<<dim3(N_NODES / 64, 1), 256, 0, stream>>>(
            gout, mlp_W + (size_t)i * HF * F_DIM, zbuf,
            gat_b + i * HF, mlp_b + i * F_DIM, N_NODES, HF, F_DIM);
        hipMemsetAsync(sums, 0, 128 * sizeof(float), stream);
        k_colstats<<<64, 256, 0, stream>>>(zbuf, sums, sumsq);
        k_bn_acc<<<N_NODES * F_DIM / 256, 256, 0, stream>>>(
            zbuf, sums, sumsq, mlp_g + i * F_DIM, mlp_beta + i * F_DIM, xacc);
    }

    // ---- pool + FC head ----
    hipMemsetAsync(pooled, 0, G_GRAPHS * F_DIM * sizeof(float), stream);
    k_pool<<<64, 256, 0, stream>>>(xacc, batch, pooled);

    k_fc<<<(64 * 256) / 256, 256, 0, stream>>>(pooled, fc1_W, fc1_b, h1, 64, 64, 256);
    k_bn_small<<<1, 256, 0, stream>>>(h1, fc1_g, fc1_beta, 64, 256, 1, h1);
    k_fc<<<(64 * 128) / 256, 256, 0, stream>>>(h1, fc2_W, fc2_b, h2, 64, 256, 128);
    k_bn_small<<<1, 128, 0, stream>>>(h2, fc2_g, fc2_beta, 64, 128, 1, h2);
    k_fc<<<3, 256, 0, stream>>>(h2, fc3_W, fc3_b, f3, 64, 128, 10);
    k_bn_small<<<1, 64, 0, stream>>>(f3, fc3_g, fc3_beta, 64, 10, 0, (float*)d_out);
}